// Round 2
// 261.548 us; speedup vs baseline: 1.0142x; 1.0142x over previous
//
#include <hip/hip_runtime.h>

#define DIM   1024
#define NH    16
#define HD    64
#define BATCH 16
#define SEQ   512
#define MROWS (BATCH*SEQ)   // 8192
#define SL2E  0.18033688011112042f   // 0.125 * log2(e)

typedef __bf16 bf16x8 __attribute__((ext_vector_type(8)));
typedef float  floatx4 __attribute__((ext_vector_type(4)));
typedef short  short4v __attribute__((ext_vector_type(4)));

static __device__ __forceinline__ unsigned short f2bf(float f) {
    union { float f; unsigned u; } v; v.f = f;
    return (unsigned short)((v.u + 0x8000u) >> 16);
}
static __device__ __forceinline__ unsigned pk2(float a, float b) {
    union { float f; unsigned u; } x, y; x.f = a; y.f = b;
    return ((x.u + 0x8000u) >> 16) | ((y.u + 0x8000u) & 0xffff0000u);
}

static __device__ __forceinline__ void glds16(const void* g, void* l) {
    __builtin_amdgcn_global_load_lds(
        (const __attribute__((address_space(1))) unsigned int*)g,
        (__attribute__((address_space(3))) unsigned int*)l, 16, 0, 0);
}

// ---------------------------------------------------------------------------
// Fused prep (unchanged, verified): [0,8192) cvt x/ctx -> bf16 ;
// [8192,12288) transpose 4 weights ; [12288,12416) RoPE cos/sin table.
// ---------------------------------------------------------------------------
__global__ __launch_bounds__(256)
void prep(const float* __restrict__ x, const float* __restrict__ ctx,
          const float* __restrict__ Wq, const float* __restrict__ Wk,
          const float* __restrict__ Wv, const float* __restrict__ Wo,
          unsigned short* __restrict__ xb, unsigned short* __restrict__ cb,
          unsigned short* __restrict__ WqT, unsigned short* __restrict__ WkT,
          unsigned short* __restrict__ WvT, unsigned short* __restrict__ WoT,
          float2* __restrict__ cstab)
{
    __shared__ float tile[32][33];
    const int blk = blockIdx.x, t = threadIdx.x;
    if (blk < 8192) {
        const float* src = (blk < 4096) ? x : ctx;
        unsigned short* dst = (blk < 4096) ? xb : cb;
        int e = ((blk & 4095) * 256 + t) * 8;
        float4 f0 = *(const float4*)&src[e];
        float4 f1 = *(const float4*)&src[e + 4];
        uint4 o = { pk2(f0.x, f0.y), pk2(f0.z, f0.w), pk2(f1.x, f1.y), pk2(f1.z, f1.w) };
        *(uint4*)&dst[e] = o;
    } else if (blk < 12288) {
        int id2 = blk - 8192;
        const float* W; unsigned short* T;
        switch (id2 >> 10) {
            case 0:  W = Wq; T = WqT; break;
            case 1:  W = Wk; T = WkT; break;
            case 2:  W = Wv; T = WvT; break;
            default: W = Wo; T = WoT; break;
        }
        int local = id2 & 1023;
        int n0 = (local & 31) * 32, k0 = (local >> 5) * 32;
        int tx = t & 31, ty = t >> 5;
        #pragma unroll
        for (int a = 0; a < 4; a++)
            tile[ty + 8 * a][tx] = W[(size_t)(k0 + ty + 8 * a) * DIM + n0 + tx];
        __syncthreads();
        #pragma unroll
        for (int a = 0; a < 4; a++)
            T[(size_t)(n0 + ty + 8 * a) * DIM + k0 + tx] = f2bf(tile[tx][ty + 8 * a]);
    } else {
        int gid = (blk - 12288) * 256 + t;   // 0 .. SEQ*HD-1
        int d = gid & (HD - 1), s = gid >> 6;
        const float C = -0.41524101186092f;  // -2*log2(10000)/64
        float f = exp2f((float)(d & 31) * C);
        float a = (float)s * f;
        cstab[gid] = make_float2(cosf(a), sinf(a));
    }
}

// ---------------------------------------------------------------------------
// GEMM v3: BM=128 x BN=256 x BK=64, 512 threads = 8 waves (2M x 4N),
// per-wave 64x64 (4x4 fragments of 16x16x32, transposed accumulate).
// LDS 96 KB: double-buffered tiles (A 16 KB, B 32 KB each).
// Per K-tile: 2 phases. Phase 1 stages group g0 of tile t+1 (A rows + B rows
// with (row&31)<16, 4 glds/wave), waits vmcnt(6) = only tile-t's g0, barrier,
// reads af[4][2] + b_even[2][2], computes ni in {0,2} (16 MFMA). Phase 2
// stages g1 (B rows with (row&31)>=16, 2 glds), vmcnt(6) = tile-t's g1,
// barrier, reads b_odd, computes ni in {1,3}. vmcnt never drained in the
// loop; loads stay in flight across every barrier (T3+T4); setprio around
// MFMA clusters (T5). WAR safety: each stage group's write-set is disjoint
// from every read a lagging wave can still have in flight (checked per phase).
// Chunk-XOR LDS swizzle identical to verified v1 (0 bank conflicts).
// ---------------------------------------------------------------------------
static __device__ __forceinline__ void gemm128x256(
    const unsigned short* __restrict__ A, const unsigned short* __restrict__ Bt,
    int m0, int n0, unsigned short* As, unsigned short* Bs, floatx4 acc[4][4])
{
    const int t = threadIdx.x;
    const int w = t >> 6, l = t & 63;
    const int wm = w >> 2, wn = w & 3;
    const int lane16 = l & 15, quad = l >> 4;
    const int lr = l >> 3;
    const int gsw = ((l & 7) ^ lr) * 8;          // pre-swizzled source col (shorts)
    const int co0 = (quad ^ (lane16 & 7)) * 8;   // fragment chunk offset, kk=0
    const int co1 = co0 ^ 32;                    // kk=1

    #pragma unroll
    for (int mi = 0; mi < 4; mi++)
        #pragma unroll
        for (int ni = 0; ni < 4; ni++) acc[mi][ni] = (floatx4){0.f, 0.f, 0.f, 0.f};

    const unsigned short* ap = A  + (size_t)(m0 + w * 16 + lr) * DIM + gsw;
    const unsigned short* bp = Bt + (size_t)(n0 + w * 32 + lr) * DIM + gsw;

    unsigned short* A0 = As;            unsigned short* A1 = As + 8192;
    unsigned short* B0 = Bs;            unsigned short* B1 = Bs + 16384;

    // prologue: tile 0 -> buf 0 (g0 then g1; 6 outstanding)
    glds16(ap,                A0 + (w * 2 + 0) * 512);
    glds16(ap + 8 * DIM,      A0 + (w * 2 + 1) * 512);
    glds16(bp,                B0 + (w * 4 + 0) * 512);
    glds16(bp + 8 * DIM,      B0 + (w * 4 + 1) * 512);
    glds16(bp + 16 * DIM,     B0 + (w * 4 + 2) * 512);
    glds16(bp + 24 * DIM,     B0 + (w * 4 + 3) * 512);

    int ktn = 64;   // K-offset (shorts) of the tile being staged
    #pragma unroll 1
    for (int tt = 0; tt < 16; ++tt) {
        // ---- phase 1: stage g0(next), wait g0(cur), compute ni even ----
        glds16(ap + ktn,            A1 + (w * 2 + 0) * 512);
        glds16(ap + 8 * DIM + ktn,  A1 + (w * 2 + 1) * 512);
        glds16(bp + ktn,            B1 + (w * 4 + 0) * 512);
        glds16(bp + 8 * DIM + ktn,  B1 + (w * 4 + 1) * 512);
        asm volatile("s_waitcnt vmcnt(6)" ::: "memory");   // cur-tile g0 landed
        __builtin_amdgcn_s_barrier();
        bf16x8 af[4][2], be[2][2];
        #pragma unroll
        for (int mi = 0; mi < 4; mi++) {
            const unsigned short* r = A0 + (wm * 64 + mi * 16 + lane16) * 64;
            af[mi][0] = *(const bf16x8*)&r[co0];
            af[mi][1] = *(const bf16x8*)&r[co1];
        }
        #pragma unroll
        for (int e = 0; e < 2; e++) {              // ni = 2e
            const unsigned short* r = B0 + (wn * 64 + e * 32 + lane16) * 64;
            be[e][0] = *(const bf16x8*)&r[co0];
            be[e][1] = *(const bf16x8*)&r[co1];
        }
        asm volatile("s_waitcnt lgkmcnt(0)" ::: "memory");
        __builtin_amdgcn_sched_barrier(0);
        __builtin_amdgcn_s_setprio(1);
        #pragma unroll
        for (int mi = 0; mi < 4; mi++) {
            acc[mi][0] = __builtin_amdgcn_mfma_f32_16x16x32_bf16(be[0][0], af[mi][0], acc[mi][0], 0, 0, 0);
            acc[mi][0] = __builtin_amdgcn_mfma_f32_16x16x32_bf16(be[0][1], af[mi][1], acc[mi][0], 0, 0, 0);
            acc[mi][2] = __builtin_amdgcn_mfma_f32_16x16x32_bf16(be[1][0], af[mi][0], acc[mi][2], 0, 0, 0);
            acc[mi][2] = __builtin_amdgcn_mfma_f32_16x16x32_bf16(be[1][1], af[mi][1], acc[mi][2], 0, 0, 0);
        }
        __builtin_amdgcn_s_setprio(0);
        // ---- phase 2: stage g1(next), wait g1(cur), compute ni odd ----
        glds16(bp + 16 * DIM + ktn, B1 + (w * 4 + 2) * 512);
        glds16(bp + 24 * DIM + ktn, B1 + (w * 4 + 3) * 512);
        asm volatile("s_waitcnt vmcnt(6)" ::: "memory");   // cur-tile g1 landed
        __builtin_amdgcn_s_barrier();
        bf16x8 bo_[2][2];
        #pragma unroll
        for (int e = 0; e < 2; e++) {              // ni = 2e+1
            const unsigned short* r = B0 + (wn * 64 + e * 32 + 16 + lane16) * 64;
            bo_[e][0] = *(const bf16x8*)&r[co0];
            bo_[e][1] = *(const bf16x8*)&r[co1];
        }
        asm volatile("s_waitcnt lgkmcnt(0)" ::: "memory");
        __builtin_amdgcn_sched_barrier(0);
        __builtin_amdgcn_s_setprio(1);
        #pragma unroll
        for (int mi = 0; mi < 4; mi++) {
            acc[mi][1] = __builtin_amdgcn_mfma_f32_16x16x32_bf16(bo_[0][0], af[mi][0], acc[mi][1], 0, 0, 0);
            acc[mi][1] = __builtin_amdgcn_mfma_f32_16x16x32_bf16(bo_[0][1], af[mi][1], acc[mi][1], 0, 0, 0);
            acc[mi][3] = __builtin_amdgcn_mfma_f32_16x16x32_bf16(bo_[1][0], af[mi][0], acc[mi][3], 0, 0, 0);
            acc[mi][3] = __builtin_amdgcn_mfma_f32_16x16x32_bf16(bo_[1][1], af[mi][1], acc[mi][3], 0, 0, 0);
        }
        __builtin_amdgcn_s_setprio(0);
        // swap buffers; tile 16 wraps to kt=0 (redundant but uniform counts)
        unsigned short* ta = A0; A0 = A1; A1 = ta;
        unsigned short* tb = B0; B0 = B1; B1 = tb;
        ktn = (ktn + 64) & (DIM - 1);
    }
    asm volatile("s_waitcnt vmcnt(0)" ::: "memory");   // drain wrap stages
}

// epilogue helper: mode 0 = rope split-head bf16, mode 1 = V^T bf16
static __device__ __forceinline__ void proj_epilogue(
    unsigned short* __restrict__ Out, const float2* __restrict__ cstab,
    int m0, int n0, int mode, floatx4 acc[4][4])
{
    const int t = threadIdx.x;
    const int w = t >> 6, l = t & 63;
    const int wm = w >> 2, wn = w & 3;
    const int lane16 = l & 15, quad = l >> 4;

    if (mode == 0) {
        #pragma unroll
        for (int mi = 0; mi < 4; mi++) {
            int m = m0 + wm * 64 + mi * 16 + lane16;
            int s = m & 511, b = m >> 9;
            #pragma unroll
            for (int ni = 0; ni < 4; ni++) {
                int n = n0 + wn * 64 + ni * 16 + quad * 4;
                int h = n >> 6, d0 = n & 63;
                const float4* cp = (const float4*)&cstab[s * HD + d0];
                float4 c01 = cp[0];   // cos[d0], sin[d0], cos[d0+1], sin[d0+1]
                float4 c23 = cp[1];
                floatx4 v = acc[mi][ni];
                float r0 = v[0] * c01.x - v[1] * c01.y;
                float r1 = fmaf(v[0], c01.w, v[1] * c01.z);
                float r2 = v[2] * c23.x - v[3] * c23.y;
                float r3 = fmaf(v[2], c23.w, v[3] * c23.z);
                uint2 o = { pk2(r0, r1), pk2(r2, r3) };
                *(uint2*)&Out[((size_t)(b * NH + h) * SEQ + s) * HD + d0] = o;
            }
        }
    } else {
        #pragma unroll
        for (int mi = 0; mi < 4; mi++) {
            int m = m0 + wm * 64 + mi * 16 + lane16;   // m = full d index
            #pragma unroll
            for (int ni = 0; ni < 4; ni++) {
                int n = n0 + wn * 64 + ni * 16 + quad * 4;   // flat (b*512+s)
                floatx4 v = acc[mi][ni];
                uint2 o = { pk2(v[0], v[1]), pk2(v[2], v[3]) };
                *(uint2*)&Out[((size_t)(n >> 9) * DIM + m) * SEQ + (n & 511)] = o;
            }
        }
    }
}

// ---------------------------------------------------------------------------
// All three projections in one launch, 768 blocks = 3 clean rounds of 256
// (1 block/CU at 96 KB LDS): [0,256) K+rope, [256,512) V^T, [512,768) Q+rope.
// XCD swizzle: blocks sharing the large-operand strip get ids congruent mod 8
// (same XCD under round-robin) and adjacent in dispatch order.
// ---------------------------------------------------------------------------
__global__ __launch_bounds__(512, 2)
void proj_qkv(const unsigned short* __restrict__ xb, const unsigned short* __restrict__ cb,
              const unsigned short* __restrict__ WqT, const unsigned short* __restrict__ WkT,
              const unsigned short* __restrict__ WvT,
              unsigned short* __restrict__ Qb, unsigned short* __restrict__ Kb,
              unsigned short* __restrict__ Vtb, const float2* __restrict__ cstab)
{
    __shared__ unsigned short As[2 * 128 * 64];   // 32 KB
    __shared__ unsigned short Bs[2 * 256 * 64];   // 64 KB
    const int id = blockIdx.x;
    const int seg = id >> 8, local = id & 255;
    const unsigned short *A, *Bt; unsigned short* Out;
    int m0, n0, mode;
    if (seg == 0)      { A = cb;  Bt = WkT; Out = Kb;  mode = 0;    // K: M=8192,N=1024
                         m0 = ((local & 7) + 8 * (local >> 5)) * 128;
                         n0 = ((local >> 3) & 3) * 256; }
    else if (seg == 1) { A = WvT; Bt = cb;  Out = Vtb; mode = 1;    // V^T: M=1024,N=8192
                         m0 = ((local >> 3) & 7) * 128;
                         n0 = ((local & 7) + 8 * (local >> 6)) * 256; }
    else               { A = xb;  Bt = WqT; Out = Qb;  mode = 0;    // Q: M=8192,N=1024
                         m0 = ((local & 7) + 8 * (local >> 5)) * 128;
                         n0 = ((local >> 3) & 3) * 256; }
    floatx4 acc[4][4];
    gemm128x256(A, Bt, m0, n0, As, Bs, acc);
    proj_epilogue(Out, cstab, m0, n0, mode, acc);
}

// ---------------------------------------------------------------------------
// Output projection: f32 out + bias, float4 stores; 256 blocks = 1 clean round.
// ---------------------------------------------------------------------------
__global__ __launch_bounds__(512, 2)
void out_gemm(const unsigned short* __restrict__ Ab, const unsigned short* __restrict__ WoT,
              float* __restrict__ O, const float* __restrict__ bias)
{
    __shared__ unsigned short As[2 * 128 * 64];
    __shared__ unsigned short Bs[2 * 256 * 64];
    const int id = blockIdx.x;
    const int m0 = ((id & 7) + 8 * (id >> 5)) * 128;
    const int n0 = ((id >> 3) & 3) * 256;
    floatx4 acc[4][4];
    gemm128x256(Ab, WoT, m0, n0, As, Bs, acc);

    const int t = threadIdx.x;
    const int w = t >> 6, l = t & 63;
    const int wm = w >> 2, wn = w & 3;
    const int lane16 = l & 15, quad = l >> 4;
    #pragma unroll
    for (int ni = 0; ni < 4; ni++) {
        int n = n0 + wn * 64 + ni * 16 + quad * 4;
        float4 bv = *(const float4*)&bias[n];
        #pragma unroll
        for (int mi = 0; mi < 4; mi++) {
            int m = m0 + wm * 64 + mi * 16 + lane16;
            floatx4 v = acc[mi][ni];
            float4 o = { v[0] + bv.x, v[1] + bv.y, v[2] + bv.z, v[3] + bv.w };
            *(float4*)&O[(size_t)m * DIM + n] = o;
        }
    }
}

// ---------------------------------------------------------------------------
// Flash attention v4 (unchanged, verified): S^T = K·Q^T, in-register P,
// operand-swapped PV, packed 8B stores.
// ---------------------------------------------------------------------------
__global__ __launch_bounds__(256, 4)
void attn_v4(const unsigned short* __restrict__ Q, const unsigned short* __restrict__ K,
             const unsigned short* __restrict__ Vt, unsigned short* __restrict__ Out)
{
    __shared__ unsigned short Qs[128][72];
    __shared__ unsigned short Ks[64][72];
    __shared__ unsigned short Vts[64][72];   // Vts[d][kv_local]

    const int id = blockIdx.x;
    const int qi = (id >> 3) & 3;
    const int bh = (id & 7) | ((id >> 5) << 3);
    const int q0 = qi * 128;
    const int t  = threadIdx.x;
    const int w = t >> 6, l = t & 63;
    const int lane16 = l & 15, quad = l >> 4;
    const size_t base = (size_t)bh * SEQ * HD;

    const int sr = t >> 3, sc = (t & 7) * 8;
    #pragma unroll
    for (int j = 0; j < 4; j++)
        *(uint4*)&Qs[j * 32 + sr][sc] =
            *(const uint4*)&Q[base + (size_t)(q0 + j * 32 + sr) * HD + sc];

    const unsigned short* kp0 = K  + base + (size_t)sr * HD + sc;
    const unsigned short* kp1 = kp0 + (size_t)32 * HD;
    const unsigned short* vp0 = Vt + base + (size_t)sr * SEQ + sc;
    const unsigned short* vp1 = vp0 + (size_t)32 * SEQ;

    floatx4 acc_o[2][4];
    float lsum[2] = {0.f, 0.f};
    #pragma unroll
    for (int st = 0; st < 2; st++)
        #pragma unroll
        for (int dt = 0; dt < 4; dt++) acc_o[st][dt] = (floatx4){0.f, 0.f, 0.f, 0.f};

    for (int kt = 0; kt < SEQ; kt += 64) {
        __syncthreads();
        *(uint4*)&Ks[sr][sc]       = *(const uint4*)kp0;  kp0 += 64 * HD;
        *(uint4*)&Ks[sr + 32][sc]  = *(const uint4*)kp1;  kp1 += 64 * HD;
        *(uint4*)&Vts[sr][sc]      = *(const uint4*)vp0;  vp0 += 64;
        *(uint4*)&Vts[sr + 32][sc] = *(const uint4*)vp1;  vp1 += 64;
        __syncthreads();

        bf16x8 kf[2][4];
        #pragma unroll
        for (int kk = 0; kk < 2; kk++)
            #pragma unroll
            for (int c = 0; c < 4; c++)
                kf[kk][c] = *(const bf16x8*)&Ks[c * 16 + lane16][kk * 32 + quad * 8];

        short4v pa[2][4];
        #pragma unroll
        for (int st = 0; st < 2; st++) {
            floatx4 sacc[4];
            #pragma unroll
            for (int c = 0; c < 4; c++) sacc[c] = (floatx4){0.f, 0.f, 0.f, 0.f};
            #pragma unroll
            for (int kk = 0; kk < 2; kk++) {
                bf16x8 qf = *(const bf16x8*)&Qs[st * 64 + w * 16 + lane16][kk * 32 + quad * 8];
                #pragma unroll
                for (int c = 0; c < 4; c++)
                    sacc[c] = __builtin_amdgcn_mfma_f32_16x16x32_bf16(kf[kk][c], qf, sacc[c], 0, 0, 0);
            }
            #pragma unroll
            for (int c = 0; c < 4; c++) {
                short4v pk;
                #pragma unroll
                for (int i = 0; i < 4; i++) {
                    float pv = exp2f(sacc[c][i] * SL2E);
                    lsum[st] += pv;
                    pk[i] = (short)f2bf(pv);
                }
                pa[st][c] = pk;
            }
        }
        #pragma unroll
        for (int c = 0; c < 4; c++) {
            #pragma unroll
            for (int dt = 0; dt < 4; dt++) {
                short4v vf = *(const short4v*)&Vts[dt * 16 + lane16][c * 16 + quad * 4];
                #pragma unroll
                for (int st = 0; st < 2; st++)
                    acc_o[st][dt] = __builtin_amdgcn_mfma_f32_16x16x16bf16_1k(
                        vf, pa[st][c], acc_o[st][dt], 0, 0, 0);
            }
        }
    }

    const int b = bh >> 4, h = bh & 15;
    #pragma unroll
    for (int st = 0; st < 2; st++) {
        float rs = lsum[st];
        rs += __shfl_xor(rs, 16, 64);
        rs += __shfl_xor(rs, 32, 64);
        float inv = 1.0f / rs;
        int s = q0 + st * 64 + w * 16 + lane16;
        size_t rowbase = (size_t)(b * SEQ + s) * DIM + h * HD;
        #pragma unroll
        for (int dt = 0; dt < 4; dt++) {
            floatx4 v = acc_o[st][dt];
            uint2 o = { pk2(v[0] * inv, v[1] * inv), pk2(v[2] * inv, v[3] * inv) };
            *(uint2*)&Out[rowbase + dt * 16 + quad * 4] = o;
        }
    }
}

// ---------------------------------------------------------------------------
extern "C" void kernel_launch(void* const* d_in, const int* in_sizes, int n_in,
                              void* d_out, int out_size, void* d_ws, size_t ws_size,
                              hipStream_t stream)
{
    const float* x   = (const float*)d_in[0];
    const float* ctx = (const float*)d_in[1];
    const float* Wq  = (const float*)d_in[2];
    const float* Wk  = (const float*)d_in[3];
    const float* Wv  = (const float*)d_in[4];
    const float* Wo  = (const float*)d_in[5];
    const float* bo  = (const float*)d_in[6];

    const size_t NW = (size_t)DIM * DIM;      // 1M elems
    const size_t NB = (size_t)MROWS * DIM;    // 8.4M elems

    unsigned short* x_bf   = (unsigned short*)d_ws;   // 16.8 MB (reused as Ab)
    unsigned short* ctx_bf = x_bf + NB;               // 16.8 MB
    unsigned short* WqT    = ctx_bf + NB;             // 2 MB each
    unsigned short* WkT    = WqT + NW;
    unsigned short* WvT    = WkT + NW;
    unsigned short* WoT    = WvT + NW;
    unsigned short* Kb     = WoT + NW;                // 16.8 MB
    unsigned short* Vtb    = Kb + NB;                 // 16.8 MB
    float2*         cstab  = (float2*)(Vtb + NB);     // 256 KB — total ~75.5 MB
    unsigned short* Qb     = (unsigned short*)d_out;  // scratch: d_out (33.5 MB) holds
                                                      // bf16 Q until out_gemm overwrites
    unsigned short* Ab     = x_bf;                    // alias: x_bf dead after proj_qkv

    prep<<<12416, 256, 0, stream>>>(x, ctx, Wq, Wk, Wv, Wo,
                                    x_bf, ctx_bf, WqT, WkT, WvT, WoT, cstab);

    proj_qkv<<<768, 512, 0, stream>>>(x_bf, ctx_bf, WqT, WkT, WvT,
                                      Qb, Kb, Vtb, cstab);

    attn_v4<<<1024, 256, 0, stream>>>(Qb, Kb, Vtb, Ab);

    out_gemm<<<256, 512, 0, stream>>>(Ab, WoT, (float*)d_out, bo);
}